// Round 1
// baseline (180.621 us; speedup 1.0000x reference)
//
#include <hip/hip_runtime.h>

// Depthwise 11x11 box blur, reflect padding, fp32, shape (16,64,256,256).
// Separable: out = kval * (11-row sum of 11-col sums). One block per
// (image, 32-row tile). Fused single pass: HBM traffic = 1 read + 1 write.

#define KS      11
#define PAD     5
#define IMG_H   256
#define IMG_W   256
#define TILE_H  32
#define RAW_ROWS (TILE_H + 2 * PAD)   // 42
#define CS_STRIDE 257                 // 256+1 pad: stage-3 reads -> 2-way (free)
#define NTILES  (IMG_H / TILE_H)      // 8

__global__ __launch_bounds__(256)
void blur_box11_kernel(const float* __restrict__ in,
                       const float* __restrict__ kern,
                       float* __restrict__ out) {
    // raw tile (42x256) later reused as result buffer (32x257 fits in 42x256)
    __shared__ float raw[RAW_ROWS * IMG_W];        // 43,008 B
    __shared__ float colsum[TILE_H * CS_STRIDE];   // 32,896 B
    float* res = raw;

    const int tid = threadIdx.x;
    const int img = blockIdx.x >> 3;               // / NTILES
    const int ty0 = (blockIdx.x & (NTILES - 1)) * TILE_H;

    const float* src = in + (size_t)img * (IMG_H * IMG_W);
    float*       dst = out + (size_t)img * (IMG_H * IMG_W);
    const float  kv  = kern[0];                    // 1/121 (uniform box kernel)

    // ---- Stage 1: global -> LDS, 42 rows with row-reflect, float4 loads ----
    // 42 rows * 64 float4 = 2688 iterations over 256 threads (coalesced).
    for (int i = tid; i < RAW_ROWS * (IMG_W / 4); i += 256) {
        int r  = i >> 6;        // / (IMG_W/4)
        int c4 = i & 63;
        int sr = ty0 + r - PAD;
        sr = (sr < 0) ? -sr : ((sr > IMG_H - 1) ? 2 * (IMG_H - 1) - sr : sr);
        float4 v = *reinterpret_cast<const float4*>(src + sr * IMG_W + c4 * 4);
        *reinterpret_cast<float4*>(&raw[r * IMG_W + c4 * 4]) = v;
    }
    __syncthreads();

    // ---- Stage 2: vertical sliding 11-sum, thread = column ----
    {
        const int x = tid;
        float s = 0.0f;
#pragma unroll
        for (int r = 0; r < KS; ++r) s += raw[r * IMG_W + x];
        colsum[x] = s;
        for (int y = 1; y < TILE_H; ++y) {
            s += raw[(y + KS - 1) * IMG_W + x] - raw[(y - 1) * IMG_W + x];
            colsum[y * CS_STRIDE + x] = s;
        }
    }
    __syncthreads();

    // ---- Stage 3: horizontal sliding 11-sum with column reflect ----
    // thread t: row = t%32, col segment = t/32 (32 cols each).
    // LDS addr = row*257 + x  ->  bank (row + x) % 32: 32 banks x 2 lanes = free.
    {
        const int row = tid & (TILE_H - 1);
        const int seg = tid >> 5;
        const float* cs = &colsum[row * CS_STRIDE];
        float*       rr = &res[row * CS_STRIDE];
        const int x0 = seg * 32;

        float s = 0.0f;
#pragma unroll
        for (int dx = -PAD; dx <= PAD; ++dx) {
            int xi = x0 + dx;
            xi = (xi < 0) ? -xi : ((xi > IMG_W - 1) ? 2 * (IMG_W - 1) - xi : xi);
            s += cs[xi];
        }
        rr[x0] = s * kv;

        for (int c = 1; c < 32; ++c) {
            int xa = x0 + c + PAD;                 // entering tap
            xa = (xa > IMG_W - 1) ? 2 * (IMG_W - 1) - xa : xa;
            int xs = x0 + c - PAD - 1;             // leaving tap
            xs = (xs < 0) ? -xs : xs;
            s += cs[xa] - cs[xs];
            rr[x0 + c] = s * kv;
        }
    }
    __syncthreads();

    // ---- Stage 4: LDS -> global, coalesced 4B/lane ----
    for (int y = 0; y < TILE_H; ++y) {
        dst[(size_t)(ty0 + y) * IMG_W + tid] = res[y * CS_STRIDE + tid];
    }
}

extern "C" void kernel_launch(void* const* d_in, const int* in_sizes, int n_in,
                              void* d_out, int out_size, void* d_ws, size_t ws_size,
                              hipStream_t stream) {
    const float* in   = (const float*)d_in[0];
    const float* kern = (const float*)d_in[1];
    float*       out  = (float*)d_out;

    const int n_images = 16 * 64;                  // B * C
    dim3 grid(n_images * NTILES);                  // 8192 blocks
    dim3 block(256);
    blur_box11_kernel<<<grid, block, 0, stream>>>(in, kern, out);
}

// Round 2
// 137.326 us; speedup vs baseline: 1.3153x; 1.3153x over previous
//
#include <hip/hip_runtime.h>

// Depthwise 11x11 box blur, reflect padding, fp32, (16,64,256,256).
// Separable box: out = kv * Hsum11(Vsum11(x)).
// One block per (image, 32-row tile). Single LDS buffer (colsum, 32 KB),
// single __syncthreads per block -> 5 blocks/CU, 20 waves/CU.
//
// Stage A: thread = column. 42 coalesced 4B global loads (row-reflect,
//          row index wave-uniform), vertical sliding 11-sum via an 11-deep
//          register circular buffer (fully unrolled, static indices).
//          Writes colsum[32][256] to LDS (lane-contiguous, conflict-free).
// Stage B: wave's 64 lanes = 64 consecutive columns of ONE row
//          (row = tid>>6 is wave-uniform). 11 lane-contiguous LDS reads
//          (conflict-free at stride 256), direct coalesced 4B store.

#define KS      11
#define PAD     5
#define IMG_H   256
#define IMG_W   256
#define TILE_H  32
#define NTILES  (IMG_H / TILE_H)      // 8
#define RAW_ROWS (TILE_H + 2 * PAD)   // 42

__global__ __launch_bounds__(256)
void blur_box11_kernel(const float* __restrict__ in,
                       const float* __restrict__ kern,
                       float* __restrict__ out) {
    __shared__ float colsum[TILE_H * IMG_W];       // 32,768 B exactly

    const int tid = threadIdx.x;
    const int img = blockIdx.x >> 3;               // / NTILES
    const int ty0 = (blockIdx.x & (NTILES - 1)) * TILE_H;

    const float* src = in + (size_t)img * (IMG_H * IMG_W);
    float*       dst = out + (size_t)img * (IMG_H * IMG_W);
    const float  kv  = kern[0];                    // 1/121 (uniform box)

    // ---- Stage A: fused load + vertical sliding 11-sum ----
    {
        const int x = tid;                         // thread = column
        float cb[KS];                              // circular buffer, static idx
        float s = 0.0f;
#pragma unroll
        for (int r = 0; r < RAW_ROWS; ++r) {
            int sr = ty0 + r - PAD;                // wave-uniform row index
            sr = (sr < 0) ? -sr : ((sr > IMG_H - 1) ? 2 * (IMG_H - 1) - sr : sr);
            float v = src[sr * IMG_W + x];         // coalesced 4B/lane
            s += v;
            if (r >= KS) s -= cb[r % KS];          // drop row r-11
            cb[r % KS] = v;
            if (r >= KS - 1) colsum[(r - (KS - 1)) * IMG_W + x] = s;
        }
    }
    __syncthreads();

    // ---- Stage B: horizontal 11-tap + direct coalesced store ----
    {
        const int lx = tid & 63;                   // lane's column offset
        const int rq = tid >> 6;                   // 0..3, wave-uniform
#pragma unroll 2
        for (int it = 0; it < TILE_H / 4 * (IMG_W / 64); ++it) {  // 32 iters
            const int row = (it >> 2) * 4 + rq;    // wave-uniform
            const int x   = (it & 3) * 64 + lx;    // lane-contiguous
            const float* cs = &colsum[row * IMG_W];
            float s = 0.0f;
#pragma unroll
            for (int dx = -PAD; dx <= PAD; ++dx) {
                int xi = x + dx;
                xi = (xi < 0) ? -xi : ((xi > IMG_W - 1) ? 2 * (IMG_W - 1) - xi : xi);
                s += cs[xi];                       // conflict-free (contig lanes)
            }
            dst[(size_t)(ty0 + row) * IMG_W + x] = s * kv;  // coalesced 256B/wave
        }
    }
}

extern "C" void kernel_launch(void* const* d_in, const int* in_sizes, int n_in,
                              void* d_out, int out_size, void* d_ws, size_t ws_size,
                              hipStream_t stream) {
    const float* in   = (const float*)d_in[0];
    const float* kern = (const float*)d_in[1];
    float*       out  = (float*)d_out;

    const int n_images = 16 * 64;                  // B * C
    dim3 grid(n_images * NTILES);                  // 8192 blocks
    dim3 block(256);
    blur_box11_kernel<<<grid, block, 0, stream>>>(in, kern, out);
}